// Round 4
// baseline (523.619 us; speedup 1.0000x reference)
//
#include <hip/hip_runtime.h>
#include <hip/hip_bf16.h>

// Problem shape (fixed by setup_inputs)
constexpr int B = 32;
constexpr int T = 2048;     // T_prev
constexpr int H = 1024;

// attention partial-split config
constexpr int SPB   = 16;           // blocks per batch
constexpr int WPB   = 4;            // waves per block (256 threads)
constexpr int PARTS = SPB * WPB;    // 64 partials per batch
constexpr int ROWS  = T / PARTS;    // 32 rows per wave

// ---------------------------------------------------------------------------
// Kernel 1: q[b,h] = sum_o dh[b,o] * W[o,h]   (dh: [B,H], W: [H,H] row-major [o,h])
// grid = 32 blocks: 4 h-blocks x 8 o-chunks; q must be zeroed beforehand.
// ---------------------------------------------------------------------------
__global__ __launch_bounds__(256) void qk_kernel(const float* __restrict__ dh,
                                                 const float* __restrict__ W,
                                                 float* __restrict__ q) {
    const int hb = blockIdx.x & 3;        // 0..3   -> 256 h each
    const int oc = blockIdx.x >> 2;       // 0..7   -> 128 o each
    const int h  = hb * 256 + threadIdx.x;

    float acc[B];
#pragma unroll
    for (int b = 0; b < B; ++b) acc[b] = 0.f;

    const int o0 = oc * 128;
    for (int o = o0; o < o0 + 128; ++o) {
        const float w = W[(size_t)o * H + h];   // coalesced across threads
#pragma unroll
        for (int b = 0; b < B; ++b)
            acc[b] += dh[b * H + o] * w;        // thread-uniform scalar loads
    }
#pragma unroll
    for (int b = 0; b < B; ++b)
        atomicAdd(&q[b * H + h], acc[b]);
}

// ---------------------------------------------------------------------------
// Kernel 2: fused online-softmax partials + concat-copy of prev -> out cache.
// One wave (64 lanes) owns ROWS rows of one batch. Each lane holds 16 h's
// (4 x float4 at float4-index lane + 64k). Produces (m, l, acc[H]) partial.
// ---------------------------------------------------------------------------
__global__ __launch_bounds__(256) void attn_part_kernel(const float* __restrict__ prev,
                                                        const float* __restrict__ q,
                                                        float* __restrict__ out_prev,
                                                        float* __restrict__ pacc,
                                                        float* __restrict__ pml) {
    const int b    = blockIdx.x / SPB;
    const int sp   = blockIdx.x % SPB;
    const int wave = threadIdx.x >> 6;
    const int lane = threadIdx.x & 63;
    const int part = sp * WPB + wave;     // 0..PARTS-1
    const int t0   = part * ROWS;

    const float4* prev4 = (const float4*)(prev + (size_t)b * T * H);
    float4*       out4  = (float4*)(out_prev + (size_t)b * (T + 1) * H);
    const float4* q4    = (const float4*)(q + b * H);

    float4 qv[4];
#pragma unroll
    for (int k = 0; k < 4; ++k) qv[k] = q4[lane + 64 * k];

    float4 acc[4];
#pragma unroll
    for (int k = 0; k < 4; ++k) acc[k] = make_float4(0.f, 0.f, 0.f, 0.f);

    float m = -1e30f, l = 0.f;

    for (int t = t0; t < t0 + ROWS; ++t) {
        const float4* row = prev4 + (size_t)t * (H / 4);
        float4 p[4];
#pragma unroll
        for (int k = 0; k < 4; ++k) p[k] = row[lane + 64 * k];

        // fused concat-copy (same coalesced layout)
        float4* orow = out4 + (size_t)t * (H / 4);
#pragma unroll
        for (int k = 0; k < 4; ++k) orow[lane + 64 * k] = p[k];

        // partial dot over this lane's 16 h's
        float s = 0.f;
#pragma unroll
        for (int k = 0; k < 4; ++k)
            s += p[k].x * qv[k].x + p[k].y * qv[k].y + p[k].z * qv[k].z + p[k].w * qv[k].w;

        // wave-wide allreduce (64 lanes)
#pragma unroll
        for (int off = 1; off < 64; off <<= 1)
            s += __shfl_xor(s, off);

        // online softmax update
        const float mn = fmaxf(m, s);
        const float sc = __expf(m - mn);
        const float w  = __expf(s - mn);
        m = mn;
        l = l * sc + w;
#pragma unroll
        for (int k = 0; k < 4; ++k) {
            acc[k].x = acc[k].x * sc + w * p[k].x;
            acc[k].y = acc[k].y * sc + w * p[k].y;
            acc[k].z = acc[k].z * sc + w * p[k].z;
            acc[k].w = acc[k].w * sc + w * p[k].w;
        }
    }

    // store partial
    const int pid = b * PARTS + part;
    float4* pa = (float4*)(pacc + (size_t)pid * H);
#pragma unroll
    for (int k = 0; k < 4; ++k) pa[lane + 64 * k] = acc[k];
    if (lane == 0) {
        pml[pid * 2 + 0] = m;
        pml[pid * 2 + 1] = l;
    }
}

// ---------------------------------------------------------------------------
// Kernel 3: combine partials -> context [B,H]; also copy dh row into cache tail.
// grid = B blocks, 256 threads (each thread: one float4 of H).
// ---------------------------------------------------------------------------
__global__ __launch_bounds__(256) void combine_kernel(const float* __restrict__ pacc,
                                                      const float* __restrict__ pml,
                                                      const float* __restrict__ dh,
                                                      float* __restrict__ out) {
    const int b  = blockIdx.x;
    const int h4 = threadIdx.x;   // float4 index 0..255

    float M = -1e30f;
#pragma unroll 8
    for (int i = 0; i < PARTS; ++i)
        M = fmaxf(M, pml[(b * PARTS + i) * 2]);

    float L = 0.f;
#pragma unroll 8
    for (int i = 0; i < PARTS; ++i)
        L += pml[(b * PARTS + i) * 2 + 1] * __expf(pml[(b * PARTS + i) * 2] - M);
    const float invL = 1.f / L;

    float4 c = make_float4(0.f, 0.f, 0.f, 0.f);
    for (int i = 0; i < PARTS; ++i) {
        const float coef = __expf(pml[(b * PARTS + i) * 2] - M);
        const float4 a = ((const float4*)(pacc + (size_t)(b * PARTS + i) * H))[h4];
        c.x += coef * a.x;
        c.y += coef * a.y;
        c.z += coef * a.z;
        c.w += coef * a.w;
    }
    c.x *= invL; c.y *= invL; c.z *= invL; c.w *= invL;
    ((float4*)(out + (size_t)b * H))[h4] = c;

    // append dh as row T of the cache
    const float4 d = ((const float4*)(dh + (size_t)b * H))[h4];
    float* out_prev = out + (size_t)B * H;
    ((float4*)(out_prev + (size_t)b * (T + 1) * H + (size_t)T * H))[h4] = d;
}

// ---------------------------------------------------------------------------
extern "C" void kernel_launch(void* const* d_in, const int* in_sizes, int n_in,
                              void* d_out, int out_size, void* d_ws, size_t ws_size,
                              hipStream_t stream) {
    const float* dh   = (const float*)d_in[0];   // [1,B,H]  == [B,H]
    const float* prev = (const float*)d_in[1];   // [B,T,H]
    const float* W    = (const float*)d_in[2];   // [H,H]
    float* out = (float*)d_out;                  // context [B*H] ++ cache [B*(T+1)*H]

    float* q    = (float*)d_ws;                  // B*H
    float* pacc = q + (size_t)B * H;             // B*PARTS*H
    float* pml  = pacc + (size_t)B * PARTS * H;  // B*PARTS*2

    hipMemsetAsync(q, 0, (size_t)B * H * sizeof(float), stream);

    qk_kernel<<<32, 256, 0, stream>>>(dh, W, q);
    attn_part_kernel<<<B * SPB, 256, 0, stream>>>(prev, q, out + (size_t)B * H, pacc, pml);
    combine_kernel<<<B, 256, 0, stream>>>(pacc, pml, dh, out);
}